// Round 1
// 507.971 us; speedup vs baseline: 1.0978x; 1.0978x over previous
//
#include <hip/hip_runtime.h>

#define M_DIM 8192
#define N_DIM 4096
#define K_DIM 4096

typedef __attribute__((ext_vector_type(8))) __bf16 bf16x8;
typedef __attribute__((ext_vector_type(4))) float f32x4;
typedef __attribute__((ext_vector_type(8))) unsigned short u16x8;
typedef __attribute__((ext_vector_type(4))) unsigned short u16x4;

typedef const __attribute__((address_space(1))) unsigned int gu32_t;
typedef __attribute__((address_space(3))) unsigned int lu32_t;

// fp32 -> bf16 round-to-nearest-even (bit trick; exact for ints <= 256)
static __device__ __forceinline__ unsigned short f2bf(float f) {
    union { float f; unsigned int u; } v; v.f = f;
    unsigned int u = v.u;
    return (unsigned short)((u + 0x7fffu + ((u >> 16) & 1u)) >> 16);
}

#define XBLOCKS 16384   // (M*K/8)/256: 8 floats per thread (2x float4 -> 1x 16B store)

// ---------- prep: x fp32->bf16 + W int32 [K][N] -> bf16 W^T [N][K] ----------
// All paths 16B-vectorized; LDS transpose tile padded to [64][68] (8B-aligned rows).
__global__ __launch_bounds__(256) void prep_kernel(const float* __restrict__ x,
                                                   unsigned short* __restrict__ xb,
                                                   const int* __restrict__ w,
                                                   unsigned short* __restrict__ wt) {
    __shared__ unsigned short t[64][68];
    const int tid = threadIdx.x;
    if (blockIdx.x < XBLOCKS) {
        size_t g = (size_t)blockIdx.x * 256 + tid;       // 8-float chunk id
        const float4* xp = (const float4*)x;
        float4 a = xp[2 * g], b = xp[2 * g + 1];
        u16x8 o;
        o[0] = f2bf(a.x); o[1] = f2bf(a.y); o[2] = f2bf(a.z); o[3] = f2bf(a.w);
        o[4] = f2bf(b.x); o[5] = f2bf(b.y); o[6] = f2bf(b.z); o[7] = f2bf(b.w);
        *(u16x8*)&xb[g * 8] = o;
    } else {
        const int bid = blockIdx.x - XBLOCKS;
        const int n0 = (bid & 63) * 64;
        const int k0 = (bid >> 6) * 64;
#pragma unroll
        for (int p = 0; p < 4; ++p) {                    // 16B int4 loads, vector LDS writes
            int r = p * 16 + (tid >> 4);
            int c = (tid & 15) * 4;
            int4 v = *(const int4*)&w[(size_t)(k0 + r) * N_DIM + n0 + c];
            u16x4 o4;
            o4[0] = f2bf((float)v.x); o4[1] = f2bf((float)v.y);
            o4[2] = f2bf((float)v.z); o4[3] = f2bf((float)v.w);
            *(u16x4*)&t[r][c] = o4;
        }
        __syncthreads();
#pragma unroll
        for (int p = 0; p < 2; ++p) {                    // transposed read, 16B coalesced stores
            int idx = p * 256 + tid;
            int c  = idx >> 3;          // output n-row: 8 consecutive lanes share a row -> 128B segments
            int r0 = (idx & 7) * 8;     // 8 k's per thread
            u16x8 o;
#pragma unroll
            for (int j = 0; j < 8; ++j) o[j] = t[r0 + j][c];
            *(u16x8*)&wt[(size_t)(n0 + c) * K_DIM + k0 + r0] = o;
        }
    }
}

// ---------- GEMM: 256x256 tile, BK=64, 8 waves (2M x 4N), 8-phase counted-vmcnt schedule ----------
// LDS 128KB = 8 regions of 16KB: region(buf,mat,kh) = buf*4 + mat*2 + kh, each [256 rows][32 k] bf16.
// Swizzle (involution): byte ^= (rowbits 1..3) << 4  (mask depends only on byte bits 7..9, untouched)
//   -> every ds_read_b128 fragment read is 2-way (free); global_load_lds keeps a LINEAR dest and the
//      swizzle is applied by permuting the per-lane GLOBAL source address (rule #21).
// Schedule per iteration (tiles T0=2i in buf0, T1=2i+1 in buf1), compute order per tile:
//   (k0,ch0),(k0,ch1),(k1,ch1),(k1,ch0); one half-tile staged per phase:
//   P1:A(b1,k1,T1) P2:B(b1,k1,T1) P3:A(b0,k0,T0+2) P4:B(b0,k0,T0+2)+vmcnt(4)
//   P5:A(b0,k1,T0+2) P6:B(b0,k1,T0+2) P7:A(b1,k0,T1+2) P8:B(b1,k0,T1+2)+vmcnt(4)
// Every stage issues after the prior content's last read+barrier; every read is covered by a
// vmcnt(4)+barrier checkpoint (P4 covers prev P7/P8 + this P1/P2; P8 covers P3..P6).
__global__ __launch_bounds__(512, 2) void gemm256_kernel(const unsigned short* __restrict__ A,
                                                         const unsigned short* __restrict__ B,
                                                         const float* __restrict__ scaler,
                                                         float* __restrict__ C) {
    __shared__ unsigned short sm[65536];   // 128 KiB

    const int tid = threadIdx.x;

    // XCD-aware swizzle (512 = 8*64, bijective), then m-fastest so each XCD keeps a B-panel L2-resident
    const int bid  = blockIdx.x;
    const int sbid = (bid & 7) * 64 + (bid >> 3);
    const int m0   = (sbid & 31) * 256;
    const int n0   = (sbid >> 5) * 256;

    const int lane = tid & 63, wave = tid >> 6;
    const int lr   = lane & 15, quad = lane >> 4;
    const int wm   = wave >> 2, wn = wave & 3;     // 2M x 4N waves; per-wave C = 128x64

    // --- staging constants: linear LDS dest D, pre-swizzled global source (inverse = same XOR) ---
    const int d0 = tid * 16, d1 = d0 + 8192;
    const int l0 = d0 ^ ((((d0 >> 7) & 1) << 4) | (((d0 >> 8) & 1) << 5) | (((d0 >> 9) & 1) << 6));
    const int l1 = d1 ^ ((((d1 >> 7) & 1) << 4) | (((d1 >> 8) & 1) << 5) | (((d1 >> 9) & 1) << 6));
    const int srow0 = l0 >> 6, scol0 = (l0 & 63) >> 1;
    const int srow1 = l1 >> 6, scol1 = (l1 & 63) >> 1;
    const unsigned short* gA0 = A + (size_t)(m0 + srow0) * K_DIM + scol0;
    const unsigned short* gA1 = A + (size_t)(m0 + srow1) * K_DIM + scol1;
    const unsigned short* gB0 = B + (size_t)(n0 + srow0) * K_DIM + scol0;
    const unsigned short* gB1 = B + (size_t)(n0 + srow1) * K_DIM + scol1;
    char* smc = (char*)sm;

    // --- fragment read offsets: row = base + lr, k-chunk = quad*16B; XOR mask from lr bits 1..3 ---
    const int amask = ((lr >> 1) & 7) << 4;
    const int afo = (((wm * 128 + lr) * 64) + quad * 16) ^ amask;  // + ch*4096 + mi*1024 + region
    const int bfo = (((wn * 64  + lr) * 64) + quad * 16) ^ amask;  // + ni*1024 + region

    f32x4 acc[8][4];
#pragma unroll
    for (int i = 0; i < 8; ++i)
#pragma unroll
        for (int j = 0; j < 4; ++j) acc[i][j] = (f32x4){0.f, 0.f, 0.f, 0.f};

    bf16x8 af[4], bfr[4];

#define STAGE_A(buf, kh, kt) do { const int _ko = (kt) * 64 + (kh) * 32; \
    __builtin_amdgcn_global_load_lds((gu32_t*)(gA0 + _ko), (lu32_t*)(smc + ((buf)*4 + (kh)) * 16384 + d0), 16, 0, 0); \
    __builtin_amdgcn_global_load_lds((gu32_t*)(gA1 + _ko), (lu32_t*)(smc + ((buf)*4 + (kh)) * 16384 + d1), 16, 0, 0); \
} while (0)
#define STAGE_B(buf, kh, kt) do { const int _ko = (kt) * 64 + (kh) * 32; \
    __builtin_amdgcn_global_load_lds((gu32_t*)(gB0 + _ko), (lu32_t*)(smc + ((buf)*4 + 2 + (kh)) * 16384 + d0), 16, 0, 0); \
    __builtin_amdgcn_global_load_lds((gu32_t*)(gB1 + _ko), (lu32_t*)(smc + ((buf)*4 + 2 + (kh)) * 16384 + d1), 16, 0, 0); \
} while (0)
#define LOADA(buf, kh, ch) do { const char* _p = smc + ((buf)*4 + (kh)) * 16384 + (ch) * 4096 + afo; \
    _Pragma("unroll") for (int _mi = 0; _mi < 4; ++_mi) af[_mi] = *(const bf16x8*)(_p + _mi * 1024); \
} while (0)
#define LOADB(buf, kh) do { const char* _p = smc + ((buf)*4 + 2 + (kh)) * 16384 + bfo; \
    _Pragma("unroll") for (int _ni = 0; _ni < 4; ++_ni) bfr[_ni] = *(const bf16x8*)(_p + _ni * 1024); \
} while (0)
#define MFMA16(ch) do { __builtin_amdgcn_s_setprio(1); \
    _Pragma("unroll") for (int _mi = 0; _mi < 4; ++_mi) \
    _Pragma("unroll") for (int _ni = 0; _ni < 4; ++_ni) \
        acc[(ch)*4 + _mi][_ni] = __builtin_amdgcn_mfma_f32_16x16x32_bf16(af[_mi], bfr[_ni], acc[(ch)*4 + _mi][_ni], 0, 0, 0); \
    __builtin_amdgcn_s_setprio(0); \
} while (0)
#define BARRIER __builtin_amdgcn_s_barrier()
#define WAITL   asm volatile("s_waitcnt lgkmcnt(0)" ::: "memory")
#define WAITV4  asm volatile("s_waitcnt vmcnt(4)" ::: "memory")

    // prologue: tile0 (both k-halves) + tile1 k0; drain once, then never vmcnt(0) in the loop
    STAGE_A(0, 0, 0); STAGE_B(0, 0, 0);
    STAGE_A(0, 1, 0); STAGE_B(0, 1, 0);
    STAGE_A(1, 0, 1); STAGE_B(1, 0, 1);
    asm volatile("s_waitcnt vmcnt(0)" ::: "memory");
    BARRIER;

    for (int i = 0; i < K_DIM / 128; ++i) {   // 32 iterations, 2 K-tiles each
        const int t1 = 2 * i + 1;
        // P1
        LOADA(0, 0, 0); LOADB(0, 0);
        STAGE_A(1, 1, t1);
        BARRIER; WAITL; MFMA16(0); BARRIER;
        // P2
        LOADA(0, 0, 1);
        STAGE_B(1, 1, t1);
        BARRIER; WAITL; MFMA16(1); BARRIER;
        // P3
        LOADA(0, 1, 1); LOADB(0, 1);
        STAGE_A(0, 0, (t1 + 1) & 63);
        BARRIER; WAITL; MFMA16(1); BARRIER;
        // P4 (checkpoint)
        LOADA(0, 1, 0);
        STAGE_B(0, 0, (t1 + 1) & 63);
        BARRIER; WAITL; MFMA16(0); WAITV4; BARRIER;
        // P5
        LOADA(1, 0, 0); LOADB(1, 0);
        STAGE_A(0, 1, (t1 + 1) & 63);
        BARRIER; WAITL; MFMA16(0); BARRIER;
        // P6
        LOADA(1, 0, 1);
        STAGE_B(0, 1, (t1 + 1) & 63);
        BARRIER; WAITL; MFMA16(1); BARRIER;
        // P7
        LOADA(1, 1, 1); LOADB(1, 1);
        STAGE_A(1, 0, (t1 + 2) & 63);
        BARRIER; WAITL; MFMA16(1); BARRIER;
        // P8 (checkpoint)
        LOADA(1, 1, 0);
        STAGE_B(1, 0, (t1 + 2) & 63);
        BARRIER; WAITL; MFMA16(0); WAITV4; BARRIER;
    }
    asm volatile("s_waitcnt vmcnt(0)" ::: "memory");

    // epilogue: C/D layout (m89-verified): col = lane&15, row = (lane>>4)*4 + reg
    const float s = scaler[0];
#pragma unroll
    for (int mi = 0; mi < 8; ++mi)
#pragma unroll
        for (int ni = 0; ni < 4; ++ni) {
            const int row = m0 + wm * 128 + mi * 16 + quad * 4;
            const int col = n0 + wn * 64 + ni * 16 + lr;
            float* cp = C + (size_t)row * N_DIM + col;
#pragma unroll
            for (int r = 0; r < 4; ++r)
                cp[(size_t)r * N_DIM] = acc[mi][ni][r] * s;
        }

#undef STAGE_A
#undef STAGE_B
#undef LOADA
#undef LOADB
#undef MFMA16
#undef BARRIER
#undef WAITL
#undef WAITV4
}

extern "C" void kernel_launch(void* const* d_in, const int* in_sizes, int n_in,
                              void* d_out, int out_size, void* d_ws, size_t ws_size,
                              hipStream_t stream) {
    const float* x      = (const float*)d_in[0];
    const float* scaler = (const float*)d_in[1];
    const int*   w      = (const int*)d_in[2];
    float*       out    = (float*)d_out;

    unsigned short* xb = (unsigned short*)d_ws;                 // bf16 x   [M][K], 64 MiB
    unsigned short* wt = xb + (size_t)M_DIM * K_DIM;            // bf16 W^T [N][K], 32 MiB

    prep_kernel<<<XBLOCKS + (N_DIM / 64) * (K_DIM / 64), 256, 0, stream>>>(x, xb, w, wt);
    gemm256_kernel<<<dim3((M_DIM / 256) * (N_DIM / 256)), 512, 0, stream>>>(xb, wt, scaler, out);
}